// Round 2
// baseline (869.019 us; speedup 1.0000x reference)
//
#include <hip/hip_runtime.h>

// Problem: x (1,16,128,128,128) fp32 -> out (1,6,16,128,128,128) fp32
// out flat index = (c*6 + k)*S + d*H*W + h*W + w,  S = 128^3
// k: 0=w+1, 1=w-1, 2=h+1, 3=h-1, 4=d+1, 5=d-1 (zero-padded shifts)

#define NC 16
#define ND 128
#define NH 128
#define NW 128
#define NS (ND * NH * NW)   // 2097152

typedef float v4f __attribute__((ext_vector_type(4)));

__global__ __launch_bounds__(256) void stencil6_kernel(
    const float* __restrict__ x, float* __restrict__ out) {
    // one thread per (c, d, h, w-quad); W/4 = 32 quads per row
    const int t  = blockIdx.x * blockDim.x + threadIdx.x;
    const int wv = t & 31;          // quad index in row
    const int r  = t >> 5;
    const int h  = r & 127;
    const int r2 = r >> 7;
    const int d  = r2 & 127;
    const int c  = r2 >> 7;
    const int w  = wv << 2;

    const size_t spatial = ((size_t)d * NH + h) * NW + w;
    const float* xin = x + (size_t)c * NS + spatial;

    const v4f z4 = (v4f){0.f, 0.f, 0.f, 0.f};

    v4f   ctr = *(const v4f*)xin;
    float lft = (wv > 0)  ? xin[-1] : 0.f;
    float rgt = (wv < 31) ? xin[4]  : 0.f;
    v4f   hp  = (h < NH - 1) ? *(const v4f*)(xin + NW)      : z4;
    v4f   hm  = (h > 0)      ? *(const v4f*)(xin - NW)      : z4;
    v4f   dp  = (d < ND - 1) ? *(const v4f*)(xin + NH * NW) : z4;
    v4f   dm  = (d > 0)      ? *(const v4f*)(xin - NH * NW) : z4;

    // w-shifted vectors from register shuffle
    v4f k0 = (v4f){ctr.y, ctr.z, ctr.w, rgt};  // neighbor w+1
    v4f k1 = (v4f){lft, ctr.x, ctr.y, ctr.z};  // neighbor w-1

    float* o = out + (size_t)(c * 6) * NS + spatial;
    __builtin_nontemporal_store(k0, (v4f*)(o + 0 * (size_t)NS));
    __builtin_nontemporal_store(k1, (v4f*)(o + 1 * (size_t)NS));
    __builtin_nontemporal_store(hp, (v4f*)(o + 2 * (size_t)NS));
    __builtin_nontemporal_store(hm, (v4f*)(o + 3 * (size_t)NS));
    __builtin_nontemporal_store(dp, (v4f*)(o + 4 * (size_t)NS));
    __builtin_nontemporal_store(dm, (v4f*)(o + 5 * (size_t)NS));
}

extern "C" void kernel_launch(void* const* d_in, const int* in_sizes, int n_in,
                              void* d_out, int out_size, void* d_ws, size_t ws_size,
                              hipStream_t stream) {
    const float* x = (const float*)d_in[0];
    float* out = (float*)d_out;
    // total threads = 16 * 128 * 128 * 32 = 8,388,608
    const int threads = 256;
    const int blocks = (NC * ND * NH * (NW / 4)) / threads;  // 32768
    stencil6_kernel<<<blocks, threads, 0, stream>>>(x, out);
}